// Round 7
// baseline (176.342 us; speedup 1.0000x reference)
//
#include <hip/hip_runtime.h>
#include <math.h>

// Problem constants: BSZ=64, BEAM=8, VOCAB=50257, STEP=5
#define BSZ   64
#define BEAM  8
#define VOCAB 50257
#define NSTEP 5
#define K     16
#define DIV_RATE 0.5f
#define SPLIT 4
#define N4    (VOCAB / 4)        // 12564 float4s (+1 tail scalar)
#define SEGF4 (N4 / SPLIT)       // 3141 float4 per segment (exact: 4*3141)
#define NLOAD 12                 // 12*256 = 3072 unconditional float4/thread
#define REM   (SEGF4 - NLOAD * 256)   // 69: tid<REM does a 13th load
#define SEGCAP 128               // per-(row,seg) slot cap (observed ~40)

typedef unsigned long long u64;
typedef unsigned u32;

// order-preserving float<->uint (monotone for all non-NaN)
__device__ __forceinline__ u32 f2s(float f) {
    u32 u = __float_as_uint(f);
    return (u & 0x80000000u) ? ~u : (u | 0x80000000u);
}
__device__ __forceinline__ float s2f(u32 s) {
    u32 u = (s & 0x80000000u) ? (s ^ 0x80000000u) : ~s;
    return __uint_as_float(u);
}

// wave(64)-wide max of a u64 key (validated R1-R6)
__device__ __forceinline__ u64 wmax64(u64 k) {
#pragma unroll
    for (int off = 32; off > 0; off >>= 1) {
        u32 lo = __shfl_xor((u32)k, off, 64);
        u32 hi = __shfl_xor((u32)(k >> 32), off, 64);
        u64 o = ((u64)hi << 32) | lo;
        if (o > k) k = o;
    }
    return k;
}

// u32 ascending bitonic sort across 64 lanes (validated R3-R6)
__device__ __forceinline__ u32 bitonic64_asc(u32 v, int lane) {
#define BS32(K_, J_)                                                         \
    {                                                                        \
        u32 o = __shfl_xor(v, (J_), 64);                                     \
        bool tmin = ((lane & (J_)) == 0) == ((lane & (K_)) == 0);            \
        v = tmin ? (v < o ? v : o) : (v > o ? v : o);                        \
    }
    BS32(2, 1)
    BS32(4, 2)  BS32(4, 1)
    BS32(8, 4)  BS32(8, 2)  BS32(8, 1)
    BS32(16, 8) BS32(16, 4) BS32(16, 2) BS32(16, 1)
    BS32(32, 16) BS32(32, 8) BS32(32, 4) BS32(32, 2) BS32(32, 1)
    BS32(64, 32) BS32(64, 16) BS32(64, 8) BS32(64, 4) BS32(64, 2) BS32(64, 1)
#undef BS32
    return v;
}

// Phase 1: per (row, seg): 13 independent float4 loads kept live in regs;
// T = exact 16th largest of the 256 per-thread maxima (2 bitonic levels;
// subset property => T <= 16th largest segment element, exactly 16 owner
// threads). Owners dump register candidates >= T into LDS; ONE coalesced
// write of the unsorted list + count to a private (row,seg) slot. No global
// atomics, no sorting, no memset. key = f2s(v)<<32 | ~vocab_idx (bias is
// uniform per row => deferred to phase 2).
__global__ __launch_bounds__(256, 4) void gather(
    const float* __restrict__ lprobs, u64* __restrict__ slots,
    int* __restrict__ cnts)
{
    const int tid  = threadIdx.x;
    const int lane = tid & 63;
    const int wave = tid >> 6;       // 0..3
    const int seg  = blockIdx.x;     // 0..3
    const int row  = blockIdx.y;     // 0..511

    const float4* rp4  = (const float4*)(lprobs + (size_t)row * VOCAB);
    const float4* base = rp4 + seg * SEGF4 + tid;

    // ---- burst: 12 unconditional + 1 predicated, all independent ----
    float4 a0  = base[0];
    float4 a1  = base[256];
    float4 a2  = base[512];
    float4 a3  = base[768];
    float4 a4  = base[1024];
    float4 a5  = base[1280];
    float4 a6  = base[1536];
    float4 a7  = base[1792];
    float4 a8  = base[2048];
    float4 a9  = base[2304];
    float4 a10 = base[2560];
    float4 a11 = base[2816];
    float4 a12 = make_float4(-INFINITY, -INFINITY, -INFINITY, -INFINITY);
    if (tid < REM) a12 = base[3072];
    float extra = -INFINITY;                    // vocab tail element 50256
    if (seg == SPLIT - 1 && tid == 0) extra = ((const float*)rp4)[VOCAB - 1];

#define MAX4(v) fmaxf(fmaxf((v).x, (v).y), fmaxf((v).z, (v).w))
    float m = fmaxf(
        fmaxf(fmaxf(fmaxf(MAX4(a0), MAX4(a1)), fmaxf(MAX4(a2), MAX4(a3))),
              fmaxf(fmaxf(MAX4(a4), MAX4(a5)), fmaxf(MAX4(a6), MAX4(a7)))),
        fmaxf(fmaxf(fmaxf(MAX4(a8), MAX4(a9)), fmaxf(MAX4(a10), MAX4(a11))),
              fmaxf(MAX4(a12), extra)));
#undef MAX4

    __shared__ u32 smax[64];         // 4 waves x top-16 maxima
    __shared__ u64 sbuf[SEGCAP];
    __shared__ int scnt;
    if (tid == 0) scnt = 0;

    // level 1: per-wave top-16 of the 64 lane maxima
    u32 v0 = bitonic64_asc(f2s(m), lane);
    if (lane >= 48) smax[wave * 16 + (lane - 48)] = v0;
    __syncthreads();
    // level 2: all 4 waves redundantly sort the 64 survivors
    u32 w0 = bitonic64_asc(smax[lane], lane);
    const float T = s2f(__shfl(w0, 48, 64));   // exact 16th of 256 maxima

    // owners (exactly 16 threads) scan their REGISTERS into LDS
#define APPEND(vv, ei)                                                       \
    if ((vv) >= T) {                                                         \
        int p = atomicAdd(&scnt, 1);                                         \
        if (p < SEGCAP) sbuf[p] = ((u64)f2s(vv) << 32) | (u32)~(u32)(ei);    \
    }
#define APP4(av, c4)                                                         \
    {                                                                        \
        int b4 = 4 * (seg * SEGF4 + (c4) * 256 + tid);                       \
        APPEND((av).x, b4 + 0) APPEND((av).y, b4 + 1)                        \
        APPEND((av).z, b4 + 2) APPEND((av).w, b4 + 3)                        \
    }
    if (m >= T) {
        APP4(a0, 0)  APP4(a1, 1)  APP4(a2, 2)   APP4(a3, 3)
        APP4(a4, 4)  APP4(a5, 5)  APP4(a6, 6)   APP4(a7, 7)
        APP4(a8, 8)  APP4(a9, 9)  APP4(a10, 10) APP4(a11, 11)
        APP4(a12, 12)                             // -INF lanes never pass
        APPEND(extra, VOCAB - 1)                  // -INF unless set
    }
#undef APP4
#undef APPEND
    __syncthreads();

    // one coalesced dump + count (each (row,seg) owned by exactly one block)
    const int n = min(scnt, SEGCAP);
    u64* slot = slots + ((size_t)row * SPLIT + seg) * SEGCAP;
    if (tid < n) slot[tid] = sbuf[tid];
    if (tid == 0) cnts[row * SPLIT + seg] = n;
}

// Phase 2: block b, wave j handles row b*8+j: gather the row's ~4x40
// candidates (slot order nondeterministic-free: fixed), 16 rounds of
// reg-max + wave-argmax => exact sorted row top-16 (rank = round); bias +
// sibling penalty; wave 0 runs the validated 128->16 finale.
__global__ __launch_bounds__(512) void reduce(
    const u64* __restrict__ slots, const int* __restrict__ cnts,
    const float* __restrict__ scores, const int* __restrict__ step_ptr,
    float* __restrict__ out)
{
    const int tid  = threadIdx.x;
    const int lane = tid & 63;
    const int j    = tid >> 6;       // beam 0..7
    const int b    = blockIdx.x;
    const int row  = b * BEAM + j;
    const int step = *step_ptr;

    __shared__ u64 fkey[BEAM * K];
    __shared__ int fvid[BEAM * K];

    // gather: fixed 2 keys/lane/seg (cap 128/seg; observed ~40)
    u64 k[2 * SPLIT];
#pragma unroll
    for (int s = 0; s < SPLIT; ++s) {
        int ns = min(cnts[row * SPLIT + s], SEGCAP);
        const u64* slot = slots + ((size_t)row * SPLIT + s) * SEGCAP;
        k[2 * s]     = (lane      < ns) ? slot[lane]      : 0ull;
        k[2 * s + 1] = (lane + 64 < ns) ? slot[lane + 64] : 0ull;
    }

    u64 mine = 0;
#pragma unroll 1
    for (int it = 0; it < K; ++it) {
        u64 lm = k[0];
#pragma unroll
        for (int i = 1; i < 2 * SPLIT; ++i) lm = (k[i] > lm) ? k[i] : lm;
        u64 mm = wmax64(lm);
        if (lane == it) mine = mm;
#pragma unroll
        for (int i = 0; i < 2 * SPLIT; ++i) if (k[i] == mm) k[i] = 0;
    }

    float* out_s = out;
    float* out_i = out + BSZ * K;
    float* out_b = out + 2 * BSZ * K;

    if (step == 0) {
        // reference: top_k(lprobs[:,0,:]): idx%vocab=idx, idx//vocab=0
        if (j == 0 && lane < K) {
            out_s[b * K + lane] = s2f((u32)(mine >> 32));
            out_i[b * K + lane] = (float)(int)~(u32)mine;
            out_b[b * K + lane] = 0.0f;
        }
        return;
    }

    if (lane < K) {
        float v   = s2f((u32)(mine >> 32));
        float add = scores[row * NSTEP + step - 1];
        float sc  = v + add - (float)(lane + 1) * DIV_RATE;   // rank = lane
        int c = j * K + lane;
        fkey[c] = ((u64)f2s(sc) << 32) | (u32)(127 - c);  // lower c wins ties
        fvid[c] = (int)~(u32)mine;
    }
    __syncthreads();

    if (tid < 64) {
        u64 pa = fkey[lane];
        u64 pb = fkey[lane + 64];
        u64 m2 = 0;
#pragma unroll 1
        for (int it = 0; it < K; ++it) {
            u64 mm = wmax64(pa > pb ? pa : pb);
            if (lane == it) m2 = mm;
            if (pa == mm) pa = 0; else if (pb == mm) pb = 0;
        }
        if (lane < K) {
            int c = 127 - (int)(m2 & 0xFFFFFFFFull);
            out_s[b * K + lane] = s2f((u32)(m2 >> 32));
            out_i[b * K + lane] = (float)fvid[c];
            out_b[b * K + lane] = (float)(c >> 4);
        }
    }
}

extern "C" void kernel_launch(void* const* d_in, const int* in_sizes, int n_in,
                              void* d_out, int out_size, void* d_ws, size_t ws_size,
                              hipStream_t stream) {
    const float* lprobs = (const float*)d_in[0];
    const float* scores = (const float*)d_in[1];
    const int*   step   = (const int*)d_in[2];

    // ws layout: [0, 8KB) counts (512*4 ints, written unconditionally by
    // every gather block => no memset needed), then candidate slots
    // (512*4*128*8B = 2 MB).
    int* cnts  = (int*)d_ws;
    u64* slots = (u64*)((char*)d_ws + 8192);

    dim3 g1(SPLIT, BSZ * BEAM);
    gather<<<g1, 256, 0, stream>>>(lprobs, slots, cnts);
    reduce<<<BSZ, 512, 0, stream>>>(slots, cnts, scores, step, (float*)d_out);
}

// Round 8
// 175.413 us; speedup vs baseline: 1.0053x; 1.0053x over previous
//
#include <hip/hip_runtime.h>
#include <math.h>

// Problem constants: BSZ=64, BEAM=8, VOCAB=50257, STEP=5
#define BSZ   64
#define BEAM  8
#define VOCAB 50257
#define NSTEP 5
#define K     16
#define DIV_RATE 0.5f
#define N4    (VOCAB / 4)        // 12564 float4s (+1 tail scalar)
#define SEGF4 (N4 / 2)           // 6282 float4 per half-row (exact split)
#define REM   (SEGF4 - 12 * 512) // 138: threads with tid<REM do a 13th load
#define SBUF_CAP 1024            // LDS candidate cap (proof bound 16*53=848)
#define SEGCAP 256               // per-(row,seg) global slot cap (observed ~30)

typedef unsigned long long u64;
typedef unsigned u32;

// order-preserving float<->uint (monotone for all non-NaN)
__device__ __forceinline__ u32 f2s(float f) {
    u32 u = __float_as_uint(f);
    return (u & 0x80000000u) ? ~u : (u | 0x80000000u);
}
__device__ __forceinline__ float s2f(u32 s) {
    u32 u = (s & 0x80000000u) ? (s ^ 0x80000000u) : ~s;
    return __uint_as_float(u);
}

// wave(64)-wide max of a u64 key (validated R1-R7)
__device__ __forceinline__ u64 wmax64(u64 k) {
#pragma unroll
    for (int off = 32; off > 0; off >>= 1) {
        u32 lo = __shfl_xor((u32)k, off, 64);
        u32 hi = __shfl_xor((u32)(k >> 32), off, 64);
        u64 o = ((u64)hi << 32) | lo;
        if (o > k) k = o;
    }
    return k;
}

// u32 ascending bitonic sort across 64 lanes (validated R3-R7)
__device__ __forceinline__ u32 bitonic64_asc(u32 v, int lane) {
#define BS32(K_, J_)                                                         \
    {                                                                        \
        u32 o = __shfl_xor(v, (J_), 64);                                     \
        bool tmin = ((lane & (J_)) == 0) == ((lane & (K_)) == 0);            \
        v = tmin ? (v < o ? v : o) : (v > o ? v : o);                        \
    }
    BS32(2, 1)
    BS32(4, 2)  BS32(4, 1)
    BS32(8, 4)  BS32(8, 2)  BS32(8, 1)
    BS32(16, 8) BS32(16, 4) BS32(16, 2) BS32(16, 1)
    BS32(32, 16) BS32(32, 8) BS32(32, 4) BS32(32, 2) BS32(32, 1)
    BS32(64, 32) BS32(64, 16) BS32(64, 8) BS32(64, 4) BS32(64, 2) BS32(64, 1)
#undef BS32
    return v;
}

// Phase 1: one block per half-row (R6 geometry, measured best). 13 burst
// float4 loads/thread kept live; T = exact 16th largest of the 512 thread
// maxima via 3-level bitonic tournament (level 3 redundant on all 8 waves:
// no wave-0 serialization, 2 barriers total); owners (m >= T) scan their
// REGISTERS into LDS; one coalesced UNSORTED dump + count to a private
// (row,seg) slot. No global atomics, no memset, no phase-1 sorting.
// key = f2s(value)<<32 | ~vocab_idx (bias uniform per row => deferred).
__global__ __launch_bounds__(512, 4) void rowtop(
    const float* __restrict__ lprobs, u64* __restrict__ slots,
    int* __restrict__ cnts)
{
    const int tid  = threadIdx.x;
    const int lane = tid & 63;
    const int wave = tid >> 6;       // 0..7
    const int seg  = blockIdx.x;     // 0..1
    const int row  = blockIdx.y;     // 0..511

    const float4* rp4  = (const float4*)(lprobs + (size_t)row * VOCAB);
    const float4* base = rp4 + seg * SEGF4 + tid;

    // ---- burst: 12 unconditional + 1 predicated, all independent ----
    float4 a0  = base[0];
    float4 a1  = base[512];
    float4 a2  = base[1024];
    float4 a3  = base[1536];
    float4 a4  = base[2048];
    float4 a5  = base[2560];
    float4 a6  = base[3072];
    float4 a7  = base[3584];
    float4 a8  = base[4096];
    float4 a9  = base[4608];
    float4 a10 = base[5120];
    float4 a11 = base[5632];
    float4 a12 = make_float4(-INFINITY, -INFINITY, -INFINITY, -INFINITY);
    if (tid < REM) a12 = base[6144];
    float extra = -INFINITY;                    // vocab tail element 50256
    if (seg == 1 && tid == 0) extra = ((const float*)rp4)[VOCAB - 1];

#define MAX4(v) fmaxf(fmaxf((v).x, (v).y), fmaxf((v).z, (v).w))
    float m = fmaxf(
        fmaxf(fmaxf(fmaxf(MAX4(a0), MAX4(a1)), fmaxf(MAX4(a2), MAX4(a3))),
              fmaxf(fmaxf(MAX4(a4), MAX4(a5)), fmaxf(MAX4(a6), MAX4(a7)))),
        fmaxf(fmaxf(fmaxf(MAX4(a8), MAX4(a9)), fmaxf(MAX4(a10), MAX4(a11))),
              fmaxf(MAX4(a12), extra)));
#undef MAX4

    __shared__ u32 smax[128];        // 8 waves x top-16 maxima
    __shared__ u32 sfin[32];         // 2 x top-16 finalists
    __shared__ u64 sbuf[SBUF_CAP];
    __shared__ int scnt;
    if (tid == 0) scnt = 0;

    // level 1: per-wave top-16 of the 64 lane maxima
    u32 v0 = bitonic64_asc(f2s(m), lane);
    if (lane >= 48) smax[wave * 16 + (lane - 48)] = v0;
    __syncthreads();

    // level 2: waves 0,1 reduce 64 survivors each -> 16 finalists each
    if (wave < 2) {
        u32 w = bitonic64_asc(smax[wave * 64 + lane], lane);
        if (lane >= 48) sfin[wave * 16 + (lane - 48)] = w;
    }
    __syncthreads();

    // level 3: ALL waves redundantly sort the 32 finalists; lane 48 = x16
    u32 w3 = bitonic64_asc(lane < 32 ? sfin[lane] : 0u, lane);
    const float T = s2f(__shfl(w3, 48, 64));    // exact 16th of 512 maxima

    // ---- owners (m >= T) scan their REGISTERS into LDS ----
#define APPEND(vv, ei)                                                       \
    if ((vv) >= T) {                                                         \
        int p = atomicAdd(&scnt, 1);                                         \
        if (p < SBUF_CAP) sbuf[p] = ((u64)f2s(vv) << 32) | (u32)~(u32)(ei);  \
    }
#define APP4(av, c4)                                                         \
    {                                                                        \
        int b4 = 4 * (seg * SEGF4 + (c4) * 512 + tid);                       \
        APPEND((av).x, b4 + 0) APPEND((av).y, b4 + 1)                        \
        APPEND((av).z, b4 + 2) APPEND((av).w, b4 + 3)                        \
    }
    if (m >= T) {
        APP4(a0, 0)  APP4(a1, 1)  APP4(a2, 2)   APP4(a3, 3)
        APP4(a4, 4)  APP4(a5, 5)  APP4(a6, 6)   APP4(a7, 7)
        APP4(a8, 8)  APP4(a9, 9)  APP4(a10, 10) APP4(a11, 11)
        APP4(a12, 12)                             // -INF lanes never pass
        APPEND(extra, VOCAB - 1)                  // -INF unless set
    }
#undef APP4
#undef APPEND
    __syncthreads();

    // ---- one coalesced unsorted dump + count (private slot per block) ----
    const int n = min(scnt, SEGCAP);
    u64* slot = slots + ((size_t)row * 2 + seg) * SEGCAP;
    if (tid < n) slot[tid] = sbuf[tid];
    if (tid == 0) cnts[row * 2 + seg] = n;
}

// Phase 2: block b, wave j handles row b*8+j: load the row's 2 candidate
// slots (8 keys/lane), 16 rounds of reg-max + wave-argmax => exact sorted
// row top-16 (rank = round; validated R3/R7); bias + sibling penalty;
// wave 0 runs the validated 128->16 finale.
__global__ __launch_bounds__(512) void reduce(
    const u64* __restrict__ slots, const int* __restrict__ cnts,
    const float* __restrict__ scores, const int* __restrict__ step_ptr,
    float* __restrict__ out)
{
    const int tid  = threadIdx.x;
    const int lane = tid & 63;
    const int j    = tid >> 6;       // beam 0..7
    const int b    = blockIdx.x;
    const int row  = b * BEAM + j;
    const int step = *step_ptr;

    __shared__ u64 fkey[BEAM * K];
    __shared__ int fvid[BEAM * K];

    u64 k[8];
#pragma unroll
    for (int s = 0; s < 2; ++s) {
        int ns = min(cnts[row * 2 + s], SEGCAP);
        const u64* slot = slots + ((size_t)row * 2 + s) * SEGCAP;
#pragma unroll
        for (int i = 0; i < 4; ++i) {
            int p = lane + 64 * i;
            k[4 * s + i] = (p < ns) ? slot[p] : 0ull;
        }
    }

    u64 mine = 0;
#pragma unroll 1
    for (int it = 0; it < K; ++it) {
        u64 lm = k[0];
#pragma unroll
        for (int i = 1; i < 8; ++i) lm = (k[i] > lm) ? k[i] : lm;
        u64 mm = wmax64(lm);
        if (lane == it) mine = mm;
#pragma unroll
        for (int i = 0; i < 8; ++i) if (k[i] == mm) k[i] = 0;
    }

    float* out_s = out;
    float* out_i = out + BSZ * K;
    float* out_b = out + 2 * BSZ * K;

    if (step == 0) {
        // reference: top_k(lprobs[:,0,:]): idx%vocab=idx, idx//vocab=0
        if (j == 0 && lane < K) {
            out_s[b * K + lane] = s2f((u32)(mine >> 32));
            out_i[b * K + lane] = (float)(int)~(u32)mine;
            out_b[b * K + lane] = 0.0f;
        }
        return;
    }

    if (lane < K) {
        float v   = s2f((u32)(mine >> 32));
        float add = scores[row * NSTEP + step - 1];
        float sc  = v + add - (float)(lane + 1) * DIV_RATE;   // rank = lane
        int c = j * K + lane;
        fkey[c] = ((u64)f2s(sc) << 32) | (u32)(127 - c);  // lower c wins ties
        fvid[c] = (int)~(u32)mine;
    }
    __syncthreads();

    if (tid < 64) {
        u64 pa = fkey[lane];
        u64 pb = fkey[lane + 64];
        u64 m2 = 0;
#pragma unroll 1
        for (int it = 0; it < K; ++it) {
            u64 mm = wmax64(pa > pb ? pa : pb);
            if (lane == it) m2 = mm;
            if (pa == mm) pa = 0; else if (pb == mm) pb = 0;
        }
        if (lane < K) {
            int c = 127 - (int)(m2 & 0xFFFFFFFFull);
            out_s[b * K + lane] = s2f((u32)(m2 >> 32));
            out_i[b * K + lane] = (float)fvid[c];
            out_b[b * K + lane] = (float)(c >> 4);
        }
    }
}

extern "C" void kernel_launch(void* const* d_in, const int* in_sizes, int n_in,
                              void* d_out, int out_size, void* d_ws, size_t ws_size,
                              hipStream_t stream) {
    const float* lprobs = (const float*)d_in[0];
    const float* scores = (const float*)d_in[1];
    const int*   step   = (const int*)d_in[2];

    // ws layout: [0, 8KB) counts (1024 ints, every block writes its own =>
    // no memset), then slots: 512 rows * 2 segs * 256 * 8 B = 2 MB.
    int* cnts  = (int*)d_ws;
    u64* slots = (u64*)((char*)d_ws + 8192);

    dim3 g1(2, BSZ * BEAM);
    rowtop<<<g1, 512, 0, stream>>>(lprobs, slots, cnts);
    reduce<<<BSZ, 512, 0, stream>>>(slots, cnts, scores, step, (float*)d_out);
}

// Round 9
// 162.715 us; speedup vs baseline: 1.0837x; 1.0780x over previous
//
#include <hip/hip_runtime.h>
#include <math.h>

// Problem constants: BSZ=64, BEAM=8, VOCAB=50257, STEP=5
// R9 = exact revert to R6 (measured best, 163.65 us): phase-1 chunked sort
// amortizes across 1024 resident blocks; phase-2 stays minimal (32-key
// bitonic + validated 128->16 finale). R7/R8 (extraction moved to phase 2)
// both regressed ~+12 us.
#define BSZ   64
#define BEAM  8
#define VOCAB 50257
#define NSTEP 5
#define K     16
#define DIV_RATE 0.5f
#define N4    (VOCAB / 4)        // 12564 float4s (+1 tail scalar)
#define SEGF4 (N4 / 2)           // 6282 float4 per half-row (exact split)
#define REM   (SEGF4 - 12 * 512) // 138: threads with tid<REM do a 13th load
#define SBUF_CAP 1024            // candidate LDS cap (proof bound 16*53=848)

typedef unsigned long long u64;
typedef unsigned u32;

// order-preserving float<->uint (monotone for all non-NaN)
__device__ __forceinline__ u32 f2s(float f) {
    u32 u = __float_as_uint(f);
    return (u & 0x80000000u) ? ~u : (u | 0x80000000u);
}
__device__ __forceinline__ float s2f(u32 s) {
    u32 u = (s & 0x80000000u) ? (s ^ 0x80000000u) : ~s;
    return __uint_as_float(u);
}

// wave(64)-wide max of a u64 key (validated R1-R8)
__device__ __forceinline__ u64 wmax64(u64 k) {
#pragma unroll
    for (int off = 32; off > 0; off >>= 1) {
        u32 lo = __shfl_xor((u32)k, off, 64);
        u32 hi = __shfl_xor((u32)(k >> 32), off, 64);
        u64 o = ((u64)hi << 32) | lo;
        if (o > k) k = o;
    }
    return k;
}

#define BSTEPS(X)                                                            \
    X(2, 1)                                                                  \
    X(4, 2)  X(4, 1)                                                         \
    X(8, 4)  X(8, 2)  X(8, 1)                                                \
    X(16, 8) X(16, 4) X(16, 2) X(16, 1)                                      \
    X(32, 16) X(32, 8) X(32, 4) X(32, 2) X(32, 1)                            \
    X(64, 32) X(64, 16) X(64, 8) X(64, 4) X(64, 2) X(64, 1)

// u32 ascending bitonic sort across 64 lanes (validated R3-R8)
__device__ __forceinline__ u32 bitonic64_asc(u32 v, int lane) {
#define BS32(K_, J_)                                                         \
    {                                                                        \
        u32 o = __shfl_xor(v, (J_), 64);                                     \
        bool tmin = ((lane & (J_)) == 0) == ((lane & (K_)) == 0);            \
        v = tmin ? (v < o ? v : o) : (v > o ? v : o);                        \
    }
    BSTEPS(BS32)
#undef BS32
    return v;
}

// u64 ascending bitonic sort across 64 lanes (same network, 2 shfl/step)
__device__ __forceinline__ u64 bitonic64_asc_u64(u64 v, int lane) {
#define BS64(K_, J_)                                                         \
    {                                                                        \
        u32 lo = __shfl_xor((u32)v, (J_), 64);                               \
        u32 hi = __shfl_xor((u32)(v >> 32), (J_), 64);                       \
        u64 o = ((u64)hi << 32) | lo;                                        \
        bool tmin = ((lane & (J_)) == 0) == ((lane & (K_)) == 0);            \
        v = tmin ? (v < o ? v : o) : (v > o ? v : o);                        \
    }
    BSTEPS(BS64)
#undef BS64
    return v;
}

// Phase 1: one block per (half-row). 13 independent float4 loads/thread kept
// live in registers; T = exact 16th largest of the 512 per-thread maxima
// (3-level bitonic tournament); owner threads (m >= T) scan registers into
// an LDS candidate list; wave 0 extracts the sorted half-row top-16 via
// chunked u64 bitonic and writes 16 keys densely.
// key = f2s(value)<<32 | ~vocab_idx (bias deferred: uniform per row).
__global__ __launch_bounds__(512, 4) void rowtop(
    const float* __restrict__ lprobs, u64* __restrict__ segk)
{
    const int tid  = threadIdx.x;
    const int lane = tid & 63;
    const int wave = tid >> 6;       // 0..7
    const int seg  = blockIdx.x;     // 0..1
    const int row  = blockIdx.y;     // 0..511

    const float4* rp4  = (const float4*)(lprobs + (size_t)row * VOCAB);
    const float4* base = rp4 + seg * SEGF4 + tid;

    // ---- burst: 12 unconditional + 1 predicated, all independent ----
    float4 a0  = base[0];
    float4 a1  = base[512];
    float4 a2  = base[1024];
    float4 a3  = base[1536];
    float4 a4  = base[2048];
    float4 a5  = base[2560];
    float4 a6  = base[3072];
    float4 a7  = base[3584];
    float4 a8  = base[4096];
    float4 a9  = base[4608];
    float4 a10 = base[5120];
    float4 a11 = base[5632];
    float4 a12 = make_float4(-INFINITY, -INFINITY, -INFINITY, -INFINITY);
    if (tid < REM) a12 = base[6144];
    float extra = -INFINITY;                    // vocab tail element 50256
    if (seg == 1 && tid == 0) extra = ((const float*)rp4)[VOCAB - 1];

#define MAX4(v) fmaxf(fmaxf((v).x, (v).y), fmaxf((v).z, (v).w))
    float m = fmaxf(
        fmaxf(fmaxf(fmaxf(MAX4(a0), MAX4(a1)), fmaxf(MAX4(a2), MAX4(a3))),
              fmaxf(fmaxf(MAX4(a4), MAX4(a5)), fmaxf(MAX4(a6), MAX4(a7)))),
        fmaxf(fmaxf(fmaxf(MAX4(a8), MAX4(a9)), fmaxf(MAX4(a10), MAX4(a11))),
              fmaxf(MAX4(a12), extra)));
#undef MAX4

    __shared__ u32 smax[128];        // 8 waves x top-16 maxima
    __shared__ u32 sfin[32];         // 2 x top-16 finalists
    __shared__ u32 sT;
    __shared__ u64 sbuf[SBUF_CAP];
    __shared__ int scnt;
    if (tid == 0) scnt = 0;

    // ---- level 1: per-wave top-16 of lane maxima ----
    u32 v0 = bitonic64_asc(f2s(m), lane);
    if (lane >= 48) smax[wave * 16 + (lane - 48)] = v0;
    __syncthreads();

    // ---- level 2: waves 0,1 each reduce 64 survivors -> 16 finalists ----
    if (wave < 2) {
        u32 w = bitonic64_asc(smax[wave * 64 + lane], lane);
        if (lane >= 48) sfin[wave * 16 + (lane - 48)] = w;
    }
    __syncthreads();

    // ---- level 3: wave 0 sorts 32 finalists; lane 48 = 16th largest ----
    if (wave == 0) {
        u32 w = bitonic64_asc(lane < 32 ? sfin[lane] : 0u, lane);
        if (lane == 48) sT = w;
    }
    __syncthreads();
    const float T = s2f(sT);

    // ---- owners (m >= T) scan their REGISTERS into LDS ----
#define APPEND(vv, ei)                                                       \
    if ((vv) >= T) {                                                         \
        int p = atomicAdd(&scnt, 1);                                         \
        if (p < SBUF_CAP) sbuf[p] = ((u64)f2s(vv) << 32) | (u32)~(u32)(ei);  \
    }
#define APP4(av, c4)                                                         \
    {                                                                        \
        int b4 = 4 * (seg * SEGF4 + (c4) * 512 + tid);                       \
        APPEND((av).x, b4 + 0) APPEND((av).y, b4 + 1)                        \
        APPEND((av).z, b4 + 2) APPEND((av).w, b4 + 3)                        \
    }
    if (m >= T) {
        APP4(a0, 0)  APP4(a1, 1)  APP4(a2, 2)   APP4(a3, 3)
        APP4(a4, 4)  APP4(a5, 5)  APP4(a6, 6)   APP4(a7, 7)
        APP4(a8, 8)  APP4(a9, 9)  APP4(a10, 10) APP4(a11, 11)
        APP4(a12, 12)                              // -INF lanes never pass
        APPEND(extra, VOCAB - 1)                   // -INF unless set
    }
#undef APP4
#undef APPEND
    __syncthreads();

    // ---- wave 0: sorted top-16 of candidates via chunked u64 bitonic ----
    if (wave == 0) {
        const int n = min(scnt, SBUF_CAP);        // n >= 16 always
        u64 run = 0;
        for (int b0 = 0; b0 < n; b0 += 48) {
            u64 v = run;                          // lanes 48..63 keep top-16
            if (lane < 48) { int p = b0 + lane; v = (p < n) ? sbuf[p] : 0; }
            v = bitonic64_asc_u64(v, lane);
            run = (lane >= 48) ? v : 0;
        }
        if (lane >= 48) {                         // rank 0 = best
            int r = 63 - lane;
            segk[((size_t)row * 2 + seg) * K + r] = run;
        }
    }
}

// Phase 2: block b, wave j: merge beam j's two sorted 16-lists (one u64
// bitonic over 32 keys + 32 zero pads; rank = lane position), apply bias +
// sibling penalty, wave 0 runs the validated 128->16 extraction.
__global__ __launch_bounds__(512) void finalize(
    const u64* __restrict__ segk, const float* __restrict__ scores,
    const int* __restrict__ step_ptr, float* __restrict__ out)
{
    const int tid  = threadIdx.x;
    const int lane = tid & 63;
    const int j    = tid >> 6;       // beam 0..7
    const int b    = blockIdx.x;
    const int row  = b * BEAM + j;
    const int step = *step_ptr;

    __shared__ u64 fkey[BEAM * K];
    __shared__ int fvid[BEAM * K];

    // merged row top-16: sort 32 real keys (unique: disjoint vocab halves)
    u64 v = (lane < 32) ? segk[(size_t)row * 32 + lane] : 0ull;
    v = bitonic64_asc_u64(v, lane);
    // lanes 48..63 hold the row top-16 ascending; rank r = 63 - lane

    float* out_s = out;
    float* out_i = out + BSZ * K;
    float* out_b = out + 2 * BSZ * K;

    if (step == 0) {
        // reference: top_k(lprobs[:,0,:]): idx%vocab=idx, idx//vocab=0
        if (j == 0 && lane >= 48) {
            int r = 63 - lane;
            out_s[b * K + r] = s2f((u32)(v >> 32));
            out_i[b * K + r] = (float)(int)~(u32)v;
            out_b[b * K + r] = 0.0f;
        }
        return;
    }

    if (lane >= 48) {
        int r = 63 - lane;
        float val = s2f((u32)(v >> 32));
        float add = scores[row * NSTEP + step - 1];
        float sc  = val + add - (float)(r + 1) * DIV_RATE;
        int c = j * K + r;
        fkey[c] = ((u64)f2s(sc) << 32) | (u32)(127 - c);  // lower c wins ties
        fvid[c] = (int)~(u32)v;
    }
    __syncthreads();

    if (tid < 64) {
        u64 pa = fkey[lane];
        u64 pb = fkey[lane + 64];
        u64 m2 = 0;
#pragma unroll 1
        for (int it = 0; it < K; ++it) {
            u64 mm = wmax64(pa > pb ? pa : pb);
            if (lane == it) m2 = mm;
            if (pa == mm) pa = 0; else if (pb == mm) pb = 0;
        }
        if (lane < K) {
            int c = 127 - (int)(m2 & 0xFFFFFFFFull);
            out_s[b * K + lane] = s2f((u32)(m2 >> 32));
            out_i[b * K + lane] = (float)fvid[c];
            out_b[b * K + lane] = (float)(c >> 4);
        }
    }
}

extern "C" void kernel_launch(void* const* d_in, const int* in_sizes, int n_in,
                              void* d_out, int out_size, void* d_ws, size_t ws_size,
                              hipStream_t stream) {
    const float* lprobs = (const float*)d_in[0];
    const float* scores = (const float*)d_in[1];
    const int*   step   = (const int*)d_in[2];

    u64* segk = (u64*)d_ws;   // 512 rows * 2 segs * 16 keys * 8 B = 128 KB

    dim3 g1(2, BSZ * BEAM);
    rowtop<<<g1, 512, 0, stream>>>(lprobs, segk);
    finalize<<<BSZ, 512, 0, stream>>>(segk, scores, step, (float*)d_out);
}